// Round 1
// baseline (583.185 us; speedup 1.0000x reference)
//
#include <hip/hip_runtime.h>

typedef short bf8 __attribute__((ext_vector_type(8)));      // 8 bf16 bit-patterns (4 VGPR) - MFMA A/B frag
typedef float f32x4 __attribute__((ext_vector_type(4)));    // MFMA C/D frag
typedef unsigned short us4 __attribute__((ext_vector_type(4)));
typedef unsigned short us8 __attribute__((ext_vector_type(8)));

#define DEVI __device__ __forceinline__

constexpr int NB = 8, NC = 512, NIC = 256, NS = 4096;   // batch, C, IC, N=H*W

// workspace layout (bytes)
constexpr size_t OFF_XT  = 0;          // xT   [8][4096][512] bf16 (x transposed, n-major)
constexpr size_t OFF_TP  = 33554432;   // tp   [8][4096][512] bf16 (cols 0-255 phiT, 256-511 thetaT)
constexpr size_t OFF_POS = 67108864;   // posb [4096][4096] bf16
constexpr size_t OFF_G   = 100663296;  // gb   [8][256][4096] bf16  (g + pos_dec, unscaled)
constexpr size_t OFF_G2  = 117440512;  // g2   [8][256][4096] bf16  (scaled by 1/s_j)
constexpr size_t OFF_Y   = 134217728;  // yb   [8][4096][256] bf16
constexpr size_t OFF_WTP = 150994944;  // wtp  [512][512] bf16 (rows 0-255 w_phi, 256-511 w_theta)
constexpr size_t OFF_WG  = 151519232;  // wgb  [256][512] bf16
constexpr size_t OFF_WM  = 151781376;  // wmb  [512][256] bf16
constexpr size_t OFF_SP  = 152043520;  // sp   [8][4][4096] f32 partial column sum-exp

DEVI unsigned short f2bf(float f){
  unsigned u = __float_as_uint(f);
  u += 0x7fffu + ((u >> 16) & 1u);   // RNE
  return (unsigned short)(u >> 16);
}
DEVI float bf2f(unsigned short b){ return __uint_as_float(((unsigned)b) << 16); }

DEVI void gld16(const void* g, void* l){
  __builtin_amdgcn_global_load_lds((const __attribute__((address_space(1))) unsigned int*)g,
                                   (__attribute__((address_space(3))) unsigned int*)l, 16, 0, 0);
}

// stage a [128 rows x 32 cols] bf16 tile, linear LDS, global_load_lds dwordx4
DEVI void stage128x32(unsigned short* dst, const unsigned short* src, int ld, int wid, int lane){
#pragma unroll
  for (int r = 0; r < 2; ++r){
    int instr = wid + r * 4;                 // 8 x 1024B
    int row = instr * 16 + (lane >> 2);
    gld16(src + (size_t)row * ld + (lane & 3) * 8, dst + instr * 512);
  }
}

DEVI void zero44(f32x4 (&a)[4][4]){
  f32x4 z = {0.f, 0.f, 0.f, 0.f};
#pragma unroll
  for (int i = 0; i < 4; ++i)
#pragma unroll
    for (int j = 0; j < 4; ++j) a[i][j] = z;
}

// 128x128 tile GEMM, K = NK*32.  A rows = m (stride lda), B rows = n (stride ldb).
// D frag (fr,fc): m = wr*64+fr*16+(lane>>4)*4+reg, n = wc*64+fc*16+(lane&15)
template<int NK>
DEVI void gemm128(const unsigned short* Ag, int lda, const unsigned short* Bg, int ldb,
                  unsigned short (&Ab)[2][4096], unsigned short (&Bb)[2][4096],
                  f32x4 (&acc)[4][4], int wid, int lane)
{
  const int wr = wid >> 1, wc = wid & 1;
  stage128x32(Ab[0], Ag, lda, wid, lane);
  stage128x32(Bb[0], Bg, ldb, wid, lane);
  __syncthreads();
  for (int kk = 0; kk < NK; ++kk){
    int cur = kk & 1;
    if (kk + 1 < NK){
      stage128x32(Ab[cur ^ 1], Ag + (kk + 1) * 32, lda, wid, lane);
      stage128x32(Bb[cur ^ 1], Bg + (kk + 1) * 32, ldb, wid, lane);
    }
    bf8 a[4], b[4];
#pragma unroll
    for (int f = 0; f < 4; ++f){
      a[f] = *(const bf8*)&Ab[cur][(wr * 64 + f * 16 + (lane & 15)) * 32 + (lane >> 4) * 8];
      b[f] = *(const bf8*)&Bb[cur][(wc * 64 + f * 16 + (lane & 15)) * 32 + (lane >> 4) * 8];
    }
#pragma unroll
    for (int i = 0; i < 4; ++i)
#pragma unroll
      for (int j = 0; j < 4; ++j)
        acc[i][j] = __builtin_amdgcn_mfma_f32_16x16x32_bf16(a[i], b[j], acc[i][j], 0, 0, 0);
    __syncthreads();
  }
}

// ---------------- small prep kernels ----------------

__global__ void k_prep(const float* wphi, const float* wtheta, const float* wgf, const float* wmf,
                       unsigned short* wtp, unsigned short* wgb, unsigned short* wmb){
  int idx = (blockIdx.x * 256 + threadIdx.x) * 4;
  const float* src; unsigned short* dst;
  if (idx < 131072)      { src = wphi + idx;            dst = wtp + idx; }
  else if (idx < 262144) { src = wtheta + (idx - 131072); dst = wtp + idx; }
  else if (idx < 393216) { src = wgf + (idx - 262144);  dst = wgb + (idx - 262144); }
  else                   { src = wmf + (idx - 393216);  dst = wmb + (idx - 393216); }
  f32x4 v = *(const f32x4*)src;
  us4 o;
#pragma unroll
  for (int r = 0; r < 4; ++r) o[r] = f2bf(v[r]);
  *(us4*)dst = o;
}

__global__ void k_pos(const float* pos, unsigned short* posb){
  size_t base = ((size_t)blockIdx.x * 256 + threadIdx.x) * 8;
  f32x4 v0 = *(const f32x4*)&pos[base];
  f32x4 v1 = *(const f32x4*)&pos[base + 4];
  us8 o;
#pragma unroll
  for (int r = 0; r < 4; ++r){ o[r] = f2bf(v0[r]); o[r + 4] = f2bf(v1[r]); }
  *(us8*)&posb[base] = o;
}

// x [b][512][4096] f32 -> xT [b][4096][512] bf16
__global__ void k_xt(const float* x, unsigned short* xT){
  int b = blockIdx.z, ct = blockIdx.y, nt = blockIdx.x;
  __shared__ float t[64][65];
  int tid = threadIdx.x;
  int c0 = ct * 64, n0 = nt * 64;
  const float* xp = x + (size_t)b * NC * NS;
#pragma unroll
  for (int it = 0; it < 16; ++it){
    int idx = it * 256 + tid; int r = idx >> 6, cc = idx & 63;
    t[r][cc] = xp[(size_t)(c0 + r) * NS + n0 + cc];
  }
  __syncthreads();
  unsigned short* xo = xT + (size_t)b * NS * NC;
#pragma unroll
  for (int it = 0; it < 16; ++it){
    int idx = it * 256 + tid; int r = idx >> 6, cc = idx & 63;
    xo[(size_t)(n0 + r) * NC + c0 + cc] = f2bf(t[cc][r]);
  }
}

// ---------------- projection GEMMs ----------------

// tp[b][n][o] = sum_c wtp[o][c] * xT[b][n][c]   (A = wtp rows o, B = xT rows n)
__global__ __launch_bounds__(256, 2) void k_tp(const unsigned short* wtp, const unsigned short* xT,
                                               unsigned short* tp){
  int b = blockIdx.z, ot = blockIdx.y, nt = blockIdx.x;
  int tid = threadIdx.x, wid = tid >> 6, lane = tid & 63, wr = wid >> 1, wc = wid & 1;
  __shared__ unsigned short Ab[2][4096], Bb[2][4096];
  f32x4 acc[4][4]; zero44(acc);
  gemm128<16>(wtp + (size_t)(ot * 128) * 512, 512,
              xT + ((size_t)b * NS + nt * 128) * 512, 512, Ab, Bb, acc, wid, lane);
  unsigned short* out = tp + (size_t)b * NS * 512;
#pragma unroll
  for (int fr = 0; fr < 4; ++fr)
#pragma unroll
    for (int fc = 0; fc < 4; ++fc){
      int o0 = ot * 128 + wr * 64 + fr * 16 + ((lane >> 4) << 2);
      int n  = nt * 128 + wc * 64 + fc * 16 + (lane & 15);
      us4 v;
#pragma unroll
      for (int r = 0; r < 4; ++r) v[r] = f2bf(acc[fr][fc][r]);
      *(us4*)&out[(size_t)n * 512 + o0] = v;
    }
}

// gb[b][o][n] = sum_c xT[b][n][c]*wgb[o][c] + pdec[o][n]   (A = xT rows n, B = wgb rows o)
__global__ __launch_bounds__(256, 2) void k_g(const unsigned short* xT, const unsigned short* wgb,
                                              const float* pdec, unsigned short* gb){
  int b = blockIdx.z, ot = blockIdx.y, nt = blockIdx.x;
  int tid = threadIdx.x, wid = tid >> 6, lane = tid & 63, wr = wid >> 1, wc = wid & 1;
  __shared__ unsigned short Ab[2][4096], Bb[2][4096];
  f32x4 acc[4][4]; zero44(acc);
  gemm128<16>(xT + ((size_t)b * NS + nt * 128) * 512, 512,
              wgb + (size_t)(ot * 128) * 512, 512, Ab, Bb, acc, wid, lane);
#pragma unroll
  for (int fr = 0; fr < 4; ++fr)
#pragma unroll
    for (int fc = 0; fc < 4; ++fc){
      int n0 = nt * 128 + wr * 64 + fr * 16 + ((lane >> 4) << 2);
      int o  = ot * 128 + wc * 64 + fc * 16 + (lane & 15);
      f32x4 pd = *(const f32x4*)&pdec[(size_t)o * NS + n0];
      us4 v;
#pragma unroll
      for (int r = 0; r < 4; ++r) v[r] = f2bf(acc[fr][fc][r] + pd[r]);
      *(us4*)&gb[((size_t)b * NIC + o) * NS + n0] = v;
    }
}

// ---------------- softmax denominators ----------------
// Lt[j][i] = sum_c phiT[j][c]*thetaT[i][c]; sp[b][ih][j] = sum_{i in chunk} exp(Lt + pos[i][j])
__global__ __launch_bounds__(256, 2) void k_stats(const unsigned short* tp, const unsigned short* posb,
                                                  float* sp){
  int b = blockIdx.z, ih = blockIdx.y, jt = blockIdx.x;
  int tid = threadIdx.x, wid = tid >> 6, lane = tid & 63, wr = wid >> 1, wc = wid & 1;
  __shared__ unsigned short Ab[2][4096], Bb[2][4096];
  __shared__ float sred[2][2][64];
  float sacc[4][4];   // [fr][r] -> local j
#pragma unroll
  for (int i = 0; i < 4; ++i)
#pragma unroll
    for (int j = 0; j < 4; ++j) sacc[i][j] = 0.f;
  const unsigned short* tpb = tp + (size_t)b * NS * 512;
  const unsigned short* Ag = tpb + (size_t)(jt * 128) * 512;         // phiT rows j
  for (int it8 = 0; it8 < 8; ++it8){
    int i0 = (ih * 8 + it8) * 128;
    const unsigned short* Bg = tpb + (size_t)i0 * 512 + 256;         // thetaT rows i
    f32x4 acc[4][4]; zero44(acc);
    gemm128<8>(Ag, 512, Bg, 512, Ab, Bb, acc, wid, lane);
#pragma unroll
    for (int fr = 0; fr < 4; ++fr)
#pragma unroll
      for (int fc = 0; fc < 4; ++fc){
        int ig  = i0 + wc * 64 + fc * 16 + (lane & 15);
        int jg0 = jt * 128 + wr * 64 + fr * 16 + ((lane >> 4) << 2);
        us4 pv = *(const us4*)&posb[(size_t)ig * NS + jg0];
#pragma unroll
        for (int r = 0; r < 4; ++r)
          sacc[fr][r] += __expf(acc[fr][fc][r] + bf2f(pv[r]));
      }
  }
#pragma unroll
  for (int m = 1; m <= 8; m <<= 1)
#pragma unroll
    for (int fr = 0; fr < 4; ++fr)
#pragma unroll
      for (int r = 0; r < 4; ++r)
        sacc[fr][r] += __shfl_xor(sacc[fr][r], m, 64);
  if ((lane & 15) == 0){
#pragma unroll
    for (int fr = 0; fr < 4; ++fr)
#pragma unroll
      for (int r = 0; r < 4; ++r)
        sred[wr][wc][fr * 16 + ((lane >> 4) << 2) + r] = sacc[fr][r];
  }
  __syncthreads();
  if (tid < 128){
    int jl = tid;
    sp[((size_t)b * 4 + ih) * NS + jt * 128 + jl] = sred[jl >> 6][0][jl & 63] + sred[jl >> 6][1][jl & 63];
  }
}

// g2 = gb / s_j
__global__ void k_sg(const unsigned short* gb, const float* sp, unsigned short* g2){
  size_t base = ((size_t)blockIdx.x * 256 + threadIdx.x) * 8;
  int b = (int)(base / ((size_t)NIC * NS));
  int j0 = (int)(base % NS);
  const float* spb = sp + (size_t)b * 4 * NS + j0;
  us8 gv = *(const us8*)&gb[base];
  us8 o;
#pragma unroll
  for (int r = 0; r < 8; ++r){
    float s = spb[r] + spb[NS + r] + spb[2 * NS + r] + spb[3 * NS + r];
    o[r] = f2bf(bf2f(gv[r]) / s);
  }
  *(us8*)&g2[base] = o;
}

// ---------------- fused  E = exp(L)  and  y = E @ g' ----------------
// per block: i-block of 64 rows; loop j-tiles of 128:
//   phase A: Lt[128 j][64 i] = phiT . thetaT^T (+pos), exp -> E_lds[64 i][128 j] bf16
//   phase B: yacc[c][i] += g2-frags (A, m=c) x E-frags (B, n=i), k=j
__global__ __launch_bounds__(256, 2) void k_y(const unsigned short* tp, const unsigned short* posb,
                                              const unsigned short* g2, unsigned short* yb){
  int b = blockIdx.y, i0 = blockIdx.x * 64;
  int tid = threadIdx.x, wid = tid >> 6, lane = tid & 63;
  __shared__ unsigned short Th[64 * 264];     // thetaT block, padded rows (264)
  __shared__ unsigned short Aph[2][4096];     // phi k-chunk dbuf
  __shared__ unsigned short El[64 * 136];     // E tile [64 i][136 j pad]
  const unsigned short* tpb = tp + (size_t)b * NS * 512;
#pragma unroll
  for (int t = 0; t < 8; ++t){
    int cid = t * 256 + tid; int row = cid >> 5, ch = cid & 31;
    *(us8*)&Th[row * 264 + ch * 8] = *(const us8*)&tpb[(size_t)(i0 + row) * 512 + 256 + ch * 8];
  }
  f32x4 yacc[4][4]; zero44(yacc);             // [cfr][ifr]
  __syncthreads();
  const unsigned short* g2b = g2 + (size_t)b * NIC * NS;
  for (int jt = 0; jt < 32; ++jt){
    int j0 = jt * 128;
    f32x4 lacc[2][4];                         // [fr][fc]: rows j (wave-split), cols i
    {
      f32x4 z = {0.f, 0.f, 0.f, 0.f};
#pragma unroll
      for (int i = 0; i < 2; ++i)
#pragma unroll
        for (int j = 0; j < 4; ++j) lacc[i][j] = z;
    }
    stage128x32(Aph[0], tpb + (size_t)j0 * 512, 512, wid, lane);
    __syncthreads();
    for (int kk = 0; kk < 8; ++kk){
      int cur = kk & 1;
      if (kk < 7) stage128x32(Aph[cur ^ 1], tpb + (size_t)j0 * 512 + (kk + 1) * 32, 512, wid, lane);
      bf8 a[2], bbf[4];
#pragma unroll
      for (int f = 0; f < 2; ++f)
        a[f] = *(const bf8*)&Aph[cur][(wid * 32 + f * 16 + (lane & 15)) * 32 + (lane >> 4) * 8];
#pragma unroll
      for (int f = 0; f < 4; ++f)
        bbf[f] = *(const bf8*)&Th[(f * 16 + (lane & 15)) * 264 + kk * 32 + (lane >> 4) * 8];
#pragma unroll
      for (int i = 0; i < 2; ++i)
#pragma unroll
        for (int j = 0; j < 4; ++j)
          lacc[i][j] = __builtin_amdgcn_mfma_f32_16x16x32_bf16(a[i], bbf[j], lacc[i][j], 0, 0, 0);
      __syncthreads();
    }
#pragma unroll
    for (int fr = 0; fr < 2; ++fr)
#pragma unroll
      for (int fc = 0; fc < 4; ++fc){
        int il  = fc * 16 + (lane & 15);
        int jl0 = wid * 32 + fr * 16 + ((lane >> 4) << 2);
        us4 pv = *(const us4*)&posb[(size_t)(i0 + il) * NS + j0 + jl0];
        us4 ev;
#pragma unroll
        for (int r = 0; r < 4; ++r)
          ev[r] = f2bf(__expf(lacc[fr][fc][r] + bf2f(pv[r])));
        *(us4*)&El[il * 136 + jl0] = ev;
      }
    __syncthreads();
#pragma unroll
    for (int jk = 0; jk < 4; ++jk){
      bf8 eb[4];
#pragma unroll
      for (int f = 0; f < 4; ++f)
        eb[f] = *(const bf8*)&El[(f * 16 + (lane & 15)) * 136 + jk * 32 + (lane >> 4) * 8];
#pragma unroll
      for (int cf = 0; cf < 4; ++cf){
        int c = wid * 64 + cf * 16 + (lane & 15);
        bf8 ga = *(const bf8*)&g2b[(size_t)c * NS + j0 + jk * 32 + (lane >> 4) * 8];
#pragma unroll
        for (int f = 0; f < 4; ++f)
          yacc[cf][f] = __builtin_amdgcn_mfma_f32_16x16x32_bf16(ga, eb[f], yacc[cf][f], 0, 0, 0);
      }
    }
    __syncthreads();
  }
  unsigned short* yo = yb + (size_t)b * NS * NIC;
#pragma unroll
  for (int cf = 0; cf < 4; ++cf)
#pragma unroll
    for (int f = 0; f < 4; ++f){
      int c0 = wid * 64 + cf * 16 + ((lane >> 4) << 2);
      int ig = i0 + f * 16 + (lane & 15);
      us4 v;
#pragma unroll
      for (int r = 0; r < 4; ++r) v[r] = f2bf(yacc[cf][f][r]);
      *(us4*)&yo[(size_t)ig * NIC + c0] = v;
    }
}

// ---------------- mask GEMM + residual ----------------
// out[b][co][n] = sum_ic yb[b][n][ic]*wmb[co][ic] + x   (A = y rows n, B = wm rows co)
__global__ __launch_bounds__(256, 2) void k_out(const unsigned short* yb, const unsigned short* wmb,
                                                const float* xg, float* outg){
  int b = blockIdx.z, cot = blockIdx.y, nt = blockIdx.x;
  int tid = threadIdx.x, wid = tid >> 6, lane = tid & 63, wr = wid >> 1, wc = wid & 1;
  __shared__ unsigned short Ab[2][4096], Bb[2][4096];
  f32x4 acc[4][4]; zero44(acc);
  gemm128<8>(yb + ((size_t)b * NS + nt * 128) * 256, 256,
             wmb + (size_t)(cot * 128) * 256, 256, Ab, Bb, acc, wid, lane);
#pragma unroll
  for (int fr = 0; fr < 4; ++fr)
#pragma unroll
    for (int fc = 0; fc < 4; ++fc){
      int n0 = nt * 128 + wr * 64 + fr * 16 + ((lane >> 4) << 2);
      int co = cot * 128 + wc * 64 + fc * 16 + (lane & 15);
      f32x4 xv = *(const f32x4*)&xg[((size_t)b * NC + co) * NS + n0];
      f32x4 ov = acc[fr][fc] + xv;
      *(f32x4*)&outg[((size_t)b * NC + co) * NS + n0] = ov;
    }
}

extern "C" void kernel_launch(void* const* d_in, const int* in_sizes, int n_in,
                              void* d_out, int out_size, void* d_ws, size_t ws_size,
                              hipStream_t stream){
  const float* x      = (const float*)d_in[0];
  const float* wphi   = (const float*)d_in[1];
  const float* wtheta = (const float*)d_in[2];
  const float* wgf    = (const float*)d_in[3];
  const float* wmf    = (const float*)d_in[4];
  const float* pos    = (const float*)d_in[5];
  const float* pdec   = (const float*)d_in[6];
  float* outg = (float*)d_out;
  char* ws = (char*)d_ws;
  unsigned short* xT   = (unsigned short*)(ws + OFF_XT);
  unsigned short* tp   = (unsigned short*)(ws + OFF_TP);
  unsigned short* posb = (unsigned short*)(ws + OFF_POS);
  unsigned short* gb   = (unsigned short*)(ws + OFF_G);
  unsigned short* g2   = (unsigned short*)(ws + OFF_G2);
  unsigned short* yb   = (unsigned short*)(ws + OFF_Y);
  unsigned short* wtp  = (unsigned short*)(ws + OFF_WTP);
  unsigned short* wgb  = (unsigned short*)(ws + OFF_WG);
  unsigned short* wmb  = (unsigned short*)(ws + OFF_WM);
  float* sp = (float*)(ws + OFF_SP);

  k_prep<<<512, 256, 0, stream>>>(wphi, wtheta, wgf, wmf, wtp, wgb, wmb);
  k_pos<<<8192, 256, 0, stream>>>(pos, posb);
  k_xt<<<dim3(64, 8, 8), 256, 0, stream>>>(x, xT);
  k_tp<<<dim3(32, 4, 8), 256, 0, stream>>>(wtp, xT, tp);
  k_g<<<dim3(32, 2, 8), 256, 0, stream>>>(xT, wgb, pdec, gb);
  k_stats<<<dim3(32, 4, 8), 256, 0, stream>>>(tp, posb, sp);
  k_sg<<<4096, 256, 0, stream>>>(gb, sp, g2);
  k_y<<<dim3(64, 8), 256, 0, stream>>>(tp, posb, g2, yb);
  k_out<<<dim3(32, 4, 8), 256, 0, stream>>>(yb, wmb, x, outg);
}